// Round 8
// baseline (471.481 us; speedup 1.0000x reference)
//
#include <hip/hip_runtime.h>

// MSDeformAttn fusion, MI355X. Round 8: conv core reverted to R4 (proven best,
// 158us, clean counters); deform vectorized to 16B gathers (8 ch/thread);
// weight repack restructured for contiguous reads.
// B=2, T=3, C=256, H=W=64, M=8, P=4, DH=32.

#define HW_SZ 4096

typedef __attribute__((ext_vector_type(8))) short short8;
typedef __attribute__((ext_vector_type(4))) float f32x4;

__device__ __forceinline__ unsigned short f2bf(float f) {
    union { float f; unsigned u; } v; v.f = f;
    unsigned u = v.u;
    unsigned r = (u + 0x7FFFu + ((u >> 16) & 1u)) >> 16;
    return (unsigned short)r;
}
__device__ __forceinline__ float bf2f(unsigned short h) {
    union { unsigned u; float f; } v; v.u = ((unsigned)h) << 16;
    return v.f;
}

__device__ __forceinline__ void gld16(const void* g, void* l) {
    __builtin_amdgcn_global_load_lds(
        (const __attribute__((address_space(1))) unsigned*)g,
        (__attribute__((address_space(3))) unsigned*)l, 16, 0, 0);
}

// ---------------- fused prep: transposes + weight repacks + biases ----------------
// repack thread = (oc, kb, lg): reads 8 ic x 9 taps (288 B contiguous),
// writes 9 x 16 B fragments to wpk [tap][ob][kb][64][8].
__device__ __forceinline__ void repack2(
    int g, const float* __restrict__ w0, const float* __restrict__ w1,
    int split, int Cout, int Cin, unsigned short* __restrict__ out, int OBp)
{
    int lg = g & 3; int rest = g >> 2;
    int KB = Cin >> 5;
    int kb = rest % KB; int oc = rest / KB;
    if (oc >= Cout) return;
    int ob = oc >> 4, l16 = oc & 15;
    const float* src = (oc < split)
        ? (w0 + ((size_t)oc * Cin + kb * 32 + lg * 8) * 9)
        : (w1 + ((size_t)(oc - split) * Cin + kb * 32 + lg * 8) * 9);
    float v[8][9];
    #pragma unroll
    for (int i = 0; i < 8; ++i)
        #pragma unroll
        for (int t = 0; t < 9; ++t)
            v[i][t] = src[i * 9 + t];
    #pragma unroll
    for (int tap = 0; tap < 9; ++tap) {
        unsigned p[4];
        #pragma unroll
        for (int j = 0; j < 4; ++j)
            p[j] = (unsigned)f2bf(v[2 * j][tap]) | ((unsigned)f2bf(v[2 * j + 1][tap]) << 16);
        uint4 o; o.x = p[0]; o.y = p[1]; o.z = p[2]; o.w = p[3];
        *(uint4*)(out + (((size_t)tap * OBp + ob) * KB + kb) * 512 + (lg * 16 + l16) * 8) = o;
    }
}

__global__ __launch_bounds__(256) void prep_fused(
    const float* __restrict__ vin_src, const float* __restrict__ qin_src,
    unsigned short* __restrict__ vdst, unsigned short* __restrict__ qdst,
    const float* __restrict__ w_value, const float* __restrict__ w_off,
    const float* __restrict__ w_attn, const float* __restrict__ w_out,
    const float* __restrict__ b_off, const float* __restrict__ b_attn,
    unsigned short* __restrict__ wpk_v, unsigned short* __restrict__ wpk_q,
    unsigned short* __restrict__ wpk_o, float* __restrict__ qbias,
    float* __restrict__ zbuf)
{
    int bid = blockIdx.x;
    if (bid < 6144) {
        int y = bid & 63, z = bid >> 6;
        const float* in; unsigned short* out; int Cin, img, kb;
        if (z < 48) { img = z >> 3; kb = z & 7; in = vin_src; out = vdst; Cin = 256; }
        else { int h = z - 48; img = h / 24; kb = h % 24; in = qin_src; out = qdst; Cin = 768; }
        __shared__ float s[32][65];
        int t = threadIdx.x;
        int x = t & 63, ic4 = t >> 6;
        const float* ip = in + ((size_t)img * Cin + kb * 32) * HW_SZ + y * 64;
        #pragma unroll
        for (int i = 0; i < 8; ++i) {
            int icl = ic4 * 8 + i;
            s[icl][x] = ip[(size_t)icl * HW_SZ + x];
        }
        __syncthreads();
        int p = t >> 2, h4 = t & 3;
        unsigned v[4];
        #pragma unroll
        for (int j = 0; j < 4; ++j) {
            unsigned lo = f2bf(s[h4 * 8 + 2 * j][p]);
            unsigned hi = f2bf(s[h4 * 8 + 2 * j + 1][p]);
            v[j] = lo | (hi << 16);
        }
        uint4 o; o.x = v[0]; o.y = v[1]; o.z = v[2]; o.w = v[3];
        *(uint4*)(out + ((size_t)img * HW_SZ + y * 64 + p) * Cin + kb * 32 + h4 * 8) = o;
    } else {
        int g = (bid - 6144) * 256 + threadIdx.x;
        if (g < 8192) {
            repack2(g, w_value, w_value, 256, 256, 256, wpk_v, 16);
        } else if (g < 35840) {
            repack2(g - 8192, w_off, w_attn, 192, 288, 768, wpk_q, 24);
        } else if (g < 44032) {
            repack2(g - 35840, w_out, w_out, 256, 256, 256, wpk_o, 16);
        } else {
            int i = g - 44032;
            if (i < 16) zbuf[i] = 0.f;
            if (i < 384) {
                float v = 0.f;
                if (i < 192) v = b_off[i]; else if (i < 288) v = b_attn[i - 192];
                qbias[i] = v;
            }
        }
    }
}

// ---------------- MFMA conv core (exact R4 structure) ----------------
// Block: 128 thr = 2 waves; wave wv = oc half. Tile: 128 oc x 64 px (row y0).
// LDS: 2 buffers x [3 rows][4 icg][66 cols] 16B units = 2 x 12672 B.
__device__ __forceinline__ void conv_core(
    const unsigned short* __restrict__ gin,
    const unsigned short* __restrict__ wpk,   // [9][OBp][KB][64][8]
    const float* __restrict__ bias,
    const unsigned short* __restrict__ zbuf,
    void* __restrict__ outp,
    int Cin, int KB, int OBp, int Cout, int mb, int y0, int outmode, int img,
    unsigned short* sbuf)
{
    const int tid = threadIdx.x;
    const int wv = tid >> 6, lane = tid & 63;
    const int l16 = lane & 15, lg = lane >> 4;
    const int obBase = mb * 8 + wv * 4;

    const unsigned short* sptr[7];
    int okk[7];
    #pragma unroll
    for (int i = 0; i < 7; ++i) {
        int ii = 2 * i + wv;
        int r = ii * 64 + lane;
        sptr[i] = zbuf; okk[i] = 0;
        if (ii < 13 && r < 792) {
            int rr = r / 264;
            int rem = r - rr * 264;
            int icg = rem / 66;
            int cc = rem - icg * 66;
            int gy = y0 - 1 + rr, gx = cc - 1;
            if ((unsigned)gy < 64u && (unsigned)gx < 64u) {
                sptr[i] = gin + ((size_t)(gy * 64 + gx)) * Cin + icg * 8;
                okk[i] = 1;
            }
        }
    }

    f32x4 acc[4][4];
    #pragma unroll
    for (int a = 0; a < 4; ++a)
        #pragma unroll
        for (int b = 0; b < 4; ++b)
            acc[a][b] = (f32x4){0.f, 0.f, 0.f, 0.f};

    auto stage = [&](int kb, unsigned short* sb) {
        #pragma unroll
        for (int i = 0; i < 7; ++i) {
            int ii = 2 * i + wv;
            int r = ii * 64 + lane;
            if (ii < 13 && r < 792) {
                const unsigned short* s = sptr[i] + (okk[i] ? (size_t)kb * 32 : 0);
                gld16(s, sb + (size_t)ii * 64 * 8);
            }
        }
    };

    stage(0, sbuf);
    for (int kb = 0; kb < KB; ++kb) {
        __syncthreads();
        if (kb + 1 < KB) stage(kb + 1, sbuf + ((kb + 1) & 1) * 6336);
        const unsigned short* cb = sbuf + (kb & 1) * 6336;
        #pragma unroll
        for (int tap = 0; tap < 9; ++tap) {
            const int ky = tap / 3, kx = tap % 3;
            short8 afr[4];
            const unsigned short* wp =
                wpk + (((size_t)tap * OBp + obBase) * KB + kb) * 512 + lane * 8;
            #pragma unroll
            for (int ob = 0; ob < 4; ++ob)
                afr[ob] = *(const short8*)(wp + (size_t)ob * KB * 512);
            short8 bfr[4];
            #pragma unroll
            for (int pt = 0; pt < 4; ++pt)
                bfr[pt] = *(const short8*)(cb + (ky * 264 + lg * 66 + kx + pt * 16 + l16) * 8);
            #pragma unroll
            for (int ob = 0; ob < 4; ++ob)
                #pragma unroll
                for (int pt = 0; pt < 4; ++pt)
                    acc[ob][pt] = __builtin_amdgcn_mfma_f32_16x16x32_bf16(
                        afr[ob], bfr[pt], acc[ob][pt], 0, 0, 0);
        }
    }

    if (outmode == 2) {
        float* outf = (float*)outp + (size_t)img * 256 * HW_SZ + (size_t)y0 * 64;
        #pragma unroll
        for (int ob = 0; ob < 4; ++ob) {
            int obg = obBase + ob;
            #pragma unroll
            for (int r = 0; r < 4; ++r) {
                int oc = obg * 16 + lg * 4 + r;
                float bv = bias[oc];
                #pragma unroll
                for (int pt = 0; pt < 4; ++pt)
                    outf[(size_t)oc * HW_SZ + pt * 16 + l16] = acc[ob][pt][r] + bv;
            }
        }
        return;
    }

    __syncthreads();
    float* s_ep = (float*)sbuf + wv * 1088;
    #pragma unroll 1
    for (int ob = 0; ob < 4; ++ob) {
        int obg = obBase + ob;
        if (obg * 16 >= Cout) continue;
        #pragma unroll
        for (int r = 0; r < 4; ++r) {
            float bv = bias ? bias[obg * 16 + lg * 4 + r] : 0.f;
            #pragma unroll
            for (int pt = 0; pt < 4; ++pt)
                s_ep[(pt * 16 + l16) * 17 + lg * 4 + r] = acc[ob][pt][r] + bv;
        }
        size_t pxg = (size_t)img * HW_SZ + (size_t)y0 * 64 + lane;
        if (outmode == 1) {
            float* op = (float*)outp + pxg * 288 + obg * 16;
            #pragma unroll
            for (int jj = 0; jj < 4; ++jj) {
                float4 t4;
                t4.x = s_ep[lane * 17 + jj * 4 + 0];
                t4.y = s_ep[lane * 17 + jj * 4 + 1];
                t4.z = s_ep[lane * 17 + jj * 4 + 2];
                t4.w = s_ep[lane * 17 + jj * 4 + 3];
                *(float4*)(op + jj * 4) = t4;
            }
        } else {
            unsigned short* op = (unsigned short*)outp + pxg * 256 + obg * 16;
            unsigned v[8];
            #pragma unroll
            for (int j = 0; j < 8; ++j) {
                unsigned lo = f2bf(s_ep[lane * 17 + 2 * j]);
                unsigned hi = f2bf(s_ep[lane * 17 + 2 * j + 1]);
                v[j] = lo | (hi << 16);
            }
            uint4 o0; o0.x = v[0]; o0.y = v[1]; o0.z = v[2]; o0.w = v[3];
            uint4 o1; o1.x = v[4]; o1.y = v[5]; o1.z = v[6]; o1.w = v[7];
            *(uint4*)(op) = o0;
            *(uint4*)(op + 8) = o1;
        }
    }
}

// merged value+qconv. g = ybase + blockIdx.y:
//   g in [0,6):  qconv  img=g/3, mb=g%3  (768->288, f32 pm, +qbias)  -- heavy, first
//   g in [6,18): value  img=(g-6)>>1, mb=(g-6)&1 (256->256, bf16 pm)
__global__ __launch_bounds__(128, 2) void conv_main(
    int ybase,
    const unsigned short* __restrict__ vin, const unsigned short* __restrict__ wv_,
    const float* __restrict__ bv, unsigned short* __restrict__ vout,
    const unsigned short* __restrict__ qin, const unsigned short* __restrict__ wq_,
    const float* __restrict__ bq, float* __restrict__ qout,
    const unsigned short* __restrict__ zbuf)
{
    __shared__ __align__(16) unsigned short sbuf[2 * 6336];
    int g = ybase + blockIdx.y;
    int y0 = blockIdx.x;
    if (g < 6) {
        int img = g / 3, mb = g - img * 3;
        conv_core(qin + (size_t)img * HW_SZ * 768, wq_, bq, zbuf, (void*)qout,
                  768, 24, 24, 288, mb, y0, 1, img, sbuf);
    } else {
        int h = g - 6; int img = h >> 1, mb = h & 1;
        conv_core(vin + (size_t)img * HW_SZ * 256, wv_, bv, zbuf, (void*)vout,
                  256, 8, 16, 256, mb, y0, 0, img, sbuf);
    }
}

// out conv: grid (64, 4) = (row, img*2+mb). NCHW f32 -> d_out.
__global__ __launch_bounds__(128, 2) void conv_out_k(
    const unsigned short* __restrict__ din, const unsigned short* __restrict__ wo_,
    const float* __restrict__ bo, float* __restrict__ outp,
    const unsigned short* __restrict__ zbuf)
{
    __shared__ __align__(16) unsigned short sbuf[2 * 6336];
    int img = blockIdx.y >> 1, mb = blockIdx.y & 1;
    conv_core(din + (size_t)img * HW_SZ * 256, wo_, bo, zbuf, (void*)outp,
              256, 8, 16, 256, mb, blockIdx.x, 2, img, sbuf);
}

// ---------------- deform sampling (8 channels / thread, 16B gathers) ----------
__global__ __launch_bounds__(256) void deform_kernel(
    const unsigned short* __restrict__ value_bf,
    const float* __restrict__ qout,
    const float* __restrict__ refp,
    const float* __restrict__ flow_fwd,
    const float* __restrict__ flow_bwd,
    unsigned short* __restrict__ dout)
{
    int gid = blockIdx.x * 256 + threadIdx.x;
    int d8 = gid & 3;
    int m = (gid >> 2) & 7;
    int q = (gid >> 5) & 4095;
    int b = gid >> 17;

    size_t bq = (size_t)b * HW_SZ + q;
    const float* qbase = qout + bq * 288;
    const float* al = qbase + 192 + m * 12;

    float lg[12];
    float mx = -1e30f;
    #pragma unroll
    for (int i = 0; i < 12; i++) { lg[i] = al[i]; mx = fmaxf(mx, lg[i]); }
    float s = 0.f;
    #pragma unroll
    for (int i = 0; i < 12; i++) { lg[i] = __expf(lg[i] - mx); s += lg[i]; }
    float inv = 1.f / s;

    const float* op = qbase + m * 24;
    const float* rp = refp + bq * 6;

    float acc[8];
    #pragma unroll
    for (int i = 0; i < 8; ++i) acc[i] = 0.f;

    #pragma unroll
    for (int t = 0; t < 3; t++) {
        float fx = 0.f, fy = 0.f;
        if (t == 0) {
            fx = flow_bwd[((b * 2 + 0) * 2 + 0) * HW_SZ + q];
            fy = flow_bwd[((b * 2 + 0) * 2 + 1) * HW_SZ + q];
        } else if (t == 2) {
            fx = flow_fwd[((b * 2 + 1) * 2 + 0) * HW_SZ + q];
            fy = flow_fwd[((b * 2 + 1) * 2 + 1) * HW_SZ + q];
        }
        float rx = rp[t * 2 + 0], ry = rp[t * 2 + 1];
        const unsigned short* vb =
            value_bf + (size_t)(b * 3 + t) * (HW_SZ * 256) + m * 32 + d8 * 8;
        #pragma unroll
        for (int pp = 0; pp < 4; pp++) {
            float ox = op[t * 8 + pp * 2 + 0] + fx;
            float oy = op[t * 8 + pp * 2 + 1] + fy;
            float aw = lg[t * 4 + pp] * inv;
            float x = rx * 64.f + ox - 0.5f;
            float y = ry * 64.f + oy - 0.5f;
            float x0f = floorf(x), y0f = floorf(y);
            float wx = x - x0f, wy = y - y0f;
            int x0 = (int)x0f, y0 = (int)y0f;
            int x1 = x0 + 1, y1 = y0 + 1;
            bool vx0 = (x0 >= 0) & (x0 < 64), vx1 = (x1 >= 0) & (x1 < 64);
            bool vy0 = (y0 >= 0) & (y0 < 64), vy1 = (y1 >= 0) & (y1 < 64);
            int cx0 = min(max(x0, 0), 63), cx1 = min(max(x1, 0), 63);
            int cy0 = min(max(y0, 0), 63), cy1 = min(max(y1, 0), 63);
            float w00 = (1.f - wx) * (1.f - wy) * ((vx0 & vy0) ? 1.f : 0.f) * aw;
            float w10 = wx * (1.f - wy) * ((vx1 & vy0) ? 1.f : 0.f) * aw;
            float w01 = (1.f - wx) * wy * ((vx0 & vy1) ? 1.f : 0.f) * aw;
            float w11 = wx * wy * ((vx1 & vy1) ? 1.f : 0.f) * aw;
            short8 v00 = *(const short8*)(vb + (cy0 * 64 + cx0) * 256);
            short8 v10 = *(const short8*)(vb + (cy0 * 64 + cx1) * 256);
            short8 v01 = *(const short8*)(vb + (cy1 * 64 + cx0) * 256);
            short8 v11 = *(const short8*)(vb + (cy1 * 64 + cx1) * 256);
            #pragma unroll
            for (int i = 0; i < 8; ++i) {
                acc[i] += w00 * bf2f((unsigned short)v00[i])
                        + w10 * bf2f((unsigned short)v10[i])
                        + w01 * bf2f((unsigned short)v01[i])
                        + w11 * bf2f((unsigned short)v11[i]);
            }
        }
    }
    unsigned pk[4];
    #pragma unroll
    for (int j = 0; j < 4; ++j)
        pk[j] = (unsigned)f2bf(acc[2 * j]) | ((unsigned)f2bf(acc[2 * j + 1]) << 16);
    uint4 o; o.x = pk[0]; o.y = pk[1]; o.z = pk[2]; o.w = pk[3];
    *(uint4*)(dout + bq * 256 + m * 32 + d8 * 8) = o;
}

extern "C" void kernel_launch(void* const* d_in, const int* in_sizes, int n_in,
                              void* d_out, int out_size, void* d_ws, size_t ws_size,
                              hipStream_t stream) {
    const float* query   = (const float*)d_in[0];
    const float* refp    = (const float*)d_in[1];
    const float* inflat  = (const float*)d_in[2];
    const float* flowf   = (const float*)d_in[6];
    const float* flowb   = (const float*)d_in[7];
    const float* w_value = (const float*)d_in[8];
    const float* b_value = (const float*)d_in[9];
    const float* w_off   = (const float*)d_in[10];
    const float* b_off   = (const float*)d_in[11];
    const float* w_attn  = (const float*)d_in[12];
    const float* b_attn  = (const float*)d_in[13];
    const float* w_out   = (const float*)d_in[14];
    const float* b_out   = (const float*)d_in[15];

    char* ws = (char*)d_ws;
    unsigned short* wpk_v    = (unsigned short*)(ws);                    // 1,179,648
    unsigned short* wpk_q    = (unsigned short*)(ws + 1179648);          // 5,308,416
    unsigned short* wpk_o    = (unsigned short*)(ws + 6488064);          // 1,179,648
    float*          qbias    = (float*)(ws + 7667712);                   // 1,536
    float*          zbuf     = (float*)(ws + 7669248);                   // 64
    unsigned short* value_bf = (unsigned short*)(ws + 7669760);          // 12,582,912
    unsigned short* qin_bf   = (unsigned short*)(ws + 20252672);         // 12,582,912
    unsigned short* vin_bf   = (unsigned short*)(ws + 32835584);         // 12,582,912

    const bool big = ws_size >= 54855680ull;
    float* qout = big ? (float*)(ws + 45418496)
                      : (float*)(ws + 32835584);   // small: over vin_bf
    unsigned short* dout_bf = big
        ? (unsigned short*)(ws + 1179648)          // over wpk_q (dead after convs)
        : (unsigned short*)(ws + 42272768);

    // 1) fused prep: transposes + weight repacks + biases
    prep_fused<<<dim3(6318), dim3(256), 0, stream>>>(
        inflat, query, vin_bf, qin_bf,
        w_value, w_off, w_attn, w_out, b_off, b_attn,
        wpk_v, wpk_q, wpk_o, qbias, zbuf);

    // 2) convs (q-groups first for tail balance)
    if (big) {
        conv_main<<<dim3(64, 18), dim3(128), 0, stream>>>(
            0, vin_bf, wpk_v, b_value, value_bf, qin_bf, wpk_q, qbias, qout,
            (const unsigned short*)zbuf);
    } else {
        // small ws: qout aliases vin_bf -> run value conv first, then qconv
        conv_main<<<dim3(64, 12), dim3(128), 0, stream>>>(
            6, vin_bf, wpk_v, b_value, value_bf, qin_bf, wpk_q, qbias, qout,
            (const unsigned short*)zbuf);
        conv_main<<<dim3(64, 6), dim3(128), 0, stream>>>(
            0, vin_bf, wpk_v, b_value, value_bf, qin_bf, wpk_q, qbias, qout,
            (const unsigned short*)zbuf);
    }

    // 3) deform sampling (8 ch/thread, 16B gathers)
    deform_kernel<<<dim3(1024), dim3(256), 0, stream>>>(
        value_bf, qout, refp, flowf, flowb, dout_bf);

    // 4) output conv -> d_out (NCHW f32)
    conv_out_k<<<dim3(64, 4), dim3(128), 0, stream>>>(
        dout_bf, wpk_o, b_out, (float*)d_out, (const unsigned short*)zbuf);
}

// Round 9
// 362.305 us; speedup vs baseline: 1.3013x; 1.3013x over previous
//
#include <hip/hip_runtime.h>

// MSDeformAttn fusion, MI355X. Round 9: conv path = verbatim R4 (the only
// allocator-stable variant: 158us, WRITE 22MB); deform = R8 16B-gather version;
// repack zero-fills wpk_q pad slots (ob 18..23) as R4 did.
// B=2, T=3, C=256, H=W=64, M=8, P=4, DH=32.

#define HW_SZ 4096

typedef __attribute__((ext_vector_type(8))) short short8;
typedef __attribute__((ext_vector_type(4))) float f32x4;

__device__ __forceinline__ unsigned short f2bf(float f) {
    union { float f; unsigned u; } v; v.f = f;
    unsigned u = v.u;
    unsigned r = (u + 0x7FFFu + ((u >> 16) & 1u)) >> 16;
    return (unsigned short)r;
}
__device__ __forceinline__ float bf2f(unsigned short h) {
    union { unsigned u; float f; } v; v.u = ((unsigned)h) << 16;
    return v.f;
}

__device__ __forceinline__ void gld16(const void* g, void* l) {
    __builtin_amdgcn_global_load_lds(
        (const __attribute__((address_space(1))) unsigned*)g,
        (__attribute__((address_space(3))) unsigned*)l, 16, 0, 0);
}

// ---------------- fused prep: transposes + weight repacks + biases ----------------
// repack thread = (oc, kb, lg): reads 8 ic x 9 taps contiguous, writes 9 fragments
// to wpk [tap][ob][kb][64][8]. oc in [Cout, OBp*16) zero-fills (pad slots).
__device__ __forceinline__ void repack2(
    int g, const float* __restrict__ w0, const float* __restrict__ w1,
    int split, int Cout, int Cin, unsigned short* __restrict__ out, int OBp)
{
    int lg = g & 3; int rest = g >> 2;
    int KB = Cin >> 5;
    int kb = rest % KB; int oc = rest / KB;
    int ob = oc >> 4, l16 = oc & 15;
    if (oc >= Cout) {
        uint4 z; z.x = z.y = z.z = z.w = 0u;
        #pragma unroll
        for (int tap = 0; tap < 9; ++tap)
            *(uint4*)(out + (((size_t)tap * OBp + ob) * KB + kb) * 512 + (lg * 16 + l16) * 8) = z;
        return;
    }
    const float* src = (oc < split)
        ? (w0 + ((size_t)oc * Cin + kb * 32 + lg * 8) * 9)
        : (w1 + ((size_t)(oc - split) * Cin + kb * 32 + lg * 8) * 9);
    float v[8][9];
    #pragma unroll
    for (int i = 0; i < 8; ++i)
        #pragma unroll
        for (int t = 0; t < 9; ++t)
            v[i][t] = src[i * 9 + t];
    #pragma unroll
    for (int tap = 0; tap < 9; ++tap) {
        unsigned p[4];
        #pragma unroll
        for (int j = 0; j < 4; ++j)
            p[j] = (unsigned)f2bf(v[2 * j][tap]) | ((unsigned)f2bf(v[2 * j + 1][tap]) << 16);
        uint4 o; o.x = p[0]; o.y = p[1]; o.z = p[2]; o.w = p[3];
        *(uint4*)(out + (((size_t)tap * OBp + ob) * KB + kb) * 512 + (lg * 16 + l16) * 8) = o;
    }
}

__global__ __launch_bounds__(256) void prep_fused(
    const float* __restrict__ vin_src, const float* __restrict__ qin_src,
    unsigned short* __restrict__ vdst, unsigned short* __restrict__ qdst,
    const float* __restrict__ w_value, const float* __restrict__ w_off,
    const float* __restrict__ w_attn, const float* __restrict__ w_out,
    const float* __restrict__ b_off, const float* __restrict__ b_attn,
    unsigned short* __restrict__ wpk_v, unsigned short* __restrict__ wpk_q,
    unsigned short* __restrict__ wpk_o, float* __restrict__ qbias,
    float* __restrict__ zbuf)
{
    int bid = blockIdx.x;
    if (bid < 6144) {
        int y = bid & 63, z = bid >> 6;
        const float* in; unsigned short* out; int Cin, img, kb;
        if (z < 48) { img = z >> 3; kb = z & 7; in = vin_src; out = vdst; Cin = 256; }
        else { int h = z - 48; img = h / 24; kb = h % 24; in = qin_src; out = qdst; Cin = 768; }
        __shared__ float s[32][65];
        int t = threadIdx.x;
        int x = t & 63, ic4 = t >> 6;
        const float* ip = in + ((size_t)img * Cin + kb * 32) * HW_SZ + y * 64;
        #pragma unroll
        for (int i = 0; i < 8; ++i) {
            int icl = ic4 * 8 + i;
            s[icl][x] = ip[(size_t)icl * HW_SZ + x];
        }
        __syncthreads();
        int p = t >> 2, h4 = t & 3;
        unsigned v[4];
        #pragma unroll
        for (int j = 0; j < 4; ++j) {
            unsigned lo = f2bf(s[h4 * 8 + 2 * j][p]);
            unsigned hi = f2bf(s[h4 * 8 + 2 * j + 1][p]);
            v[j] = lo | (hi << 16);
        }
        uint4 o; o.x = v[0]; o.y = v[1]; o.z = v[2]; o.w = v[3];
        *(uint4*)(out + ((size_t)img * HW_SZ + y * 64 + p) * Cin + kb * 32 + h4 * 8) = o;
    } else {
        int g = (bid - 6144) * 256 + threadIdx.x;
        if (g < 8192) {
            repack2(g, w_value, w_value, 256, 256, 256, wpk_v, 16);
        } else if (g < 45056) {                                  // 384 oc x 24 kb x 4
            repack2(g - 8192, w_off, w_attn, 192, 288, 768, wpk_q, 24);
        } else if (g < 53248) {
            repack2(g - 45056, w_out, w_out, 256, 256, 256, wpk_o, 16);
        } else {
            int i = g - 53248;
            if (i < 16) zbuf[i] = 0.f;
            if (i < 384) {
                float v = 0.f;
                if (i < 192) v = b_off[i]; else if (i < 288) v = b_attn[i - 192];
                qbias[i] = v;
            }
        }
    }
}

// ---------------- MFMA conv core (VERBATIM R4 — allocator-stable) ----------------
// Block: 128 thr = 2 waves; wave wv = oc half. Tile: 128 oc x 64 px (row y0).
// LDS: 2 buffers x [3 rows][4 icg][66 cols] 16B units = 2 x 12672 B.
// Weight frags: rolling 3-tap register prefetch (afr[3][4]).
__device__ __forceinline__ void conv_core(
    const unsigned short* __restrict__ gin,
    const unsigned short* __restrict__ wpk,   // [9][OBp][KB][64][8]
    const float* __restrict__ bias,
    const unsigned short* __restrict__ zbuf,
    void* __restrict__ outp,
    int Cin, int KB, int OBp, int Cout, int mb, int y0, int outmode, int img,
    unsigned short* sbuf)
{
    const int tid = threadIdx.x;
    const int wv = tid >> 6, lane = tid & 63;
    const int l16 = lane & 15, lg = lane >> 4;
    const int obBase = mb * 8 + wv * 4;

    // precompute staging sources; wave wv takes issues ii = 2i+wv (13 total)
    const unsigned short* sptr[7];
    int okk[7];
    #pragma unroll
    for (int i = 0; i < 7; ++i) {
        int ii = 2 * i + wv;
        int r = ii * 64 + lane;
        sptr[i] = zbuf; okk[i] = 0;
        if (ii < 13 && r < 792) {
            int rr = r / 264;
            int rem = r - rr * 264;
            int icg = rem / 66;
            int cc = rem - icg * 66;
            int gy = y0 - 1 + rr, gx = cc - 1;
            if ((unsigned)gy < 64u && (unsigned)gx < 64u) {
                sptr[i] = gin + ((size_t)(gy * 64 + gx)) * Cin + icg * 8;
                okk[i] = 1;
            }
        }
    }

    f32x4 acc[4][4];
    #pragma unroll
    for (int a = 0; a < 4; ++a)
        #pragma unroll
        for (int b = 0; b < 4; ++b)
            acc[a][b] = (f32x4){0.f, 0.f, 0.f, 0.f};

    auto stage = [&](int kb, unsigned short* sb) {
        #pragma unroll
        for (int i = 0; i < 7; ++i) {
            int ii = 2 * i + wv;
            int r = ii * 64 + lane;
            if (ii < 13 && r < 792) {
                const unsigned short* s = sptr[i] + (okk[i] ? (size_t)kb * 32 : 0);
                gld16(s, sb + (size_t)ii * 64 * 8);
            }
        }
    };

    short8 afr[3][4];
    auto ldA = [&](int kb, int tap, int slot) {
        const unsigned short* wp =
            wpk + (((size_t)tap * OBp + obBase) * KB + kb) * 512;
        #pragma unroll
        for (int ob = 0; ob < 4; ++ob)
            afr[slot][ob] = *(const short8*)(wp + (size_t)ob * KB * 512 + lane * 8);
    };

    stage(0, sbuf);
    for (int kb = 0; kb < KB; ++kb) {
        __syncthreads();                       // buffer kb ready (drains vmcnt)
        if (kb + 1 < KB) stage(kb + 1, sbuf + ((kb + 1) & 1) * 6336);
        ldA(kb, 0, 0); ldA(kb, 1, 1); ldA(kb, 2, 2);
        const unsigned short* cb = sbuf + (kb & 1) * 6336;
        #pragma unroll
        for (int tap = 0; tap < 9; ++tap) {
            const int ky = tap / 3, kx = tap % 3;
            const int slot = tap % 3;
            short8 bfr[4];
            #pragma unroll
            for (int pt = 0; pt < 4; ++pt)
                bfr[pt] = *(const short8*)(cb + (ky * 264 + lg * 66 + kx + pt * 16 + l16) * 8);
            #pragma unroll
            for (int ob = 0; ob < 4; ++ob)
                #pragma unroll
                for (int pt = 0; pt < 4; ++pt)
                    acc[ob][pt] = __builtin_amdgcn_mfma_f32_16x16x32_bf16(
                        afr[slot][ob], bfr[pt], acc[ob][pt], 0, 0, 0);
            if (tap < 6) ldA(kb, tap + 3, slot);
        }
    }

    if (outmode == 2) {
        float* outf = (float*)outp + (size_t)img * 256 * HW_SZ + (size_t)y0 * 64;
        #pragma unroll
        for (int ob = 0; ob < 4; ++ob) {
            int obg = obBase + ob;
            #pragma unroll
            for (int r = 0; r < 4; ++r) {
                int oc = obg * 16 + lg * 4 + r;
                float bv = bias[oc];
                #pragma unroll
                for (int pt = 0; pt < 4; ++pt)
                    outf[(size_t)oc * HW_SZ + pt * 16 + l16] = acc[ob][pt][r] + bv;
            }
        }
    } else {
        __syncthreads();                       // LDS reads done; reuse for epilogue
        float* s_ep = (float*)sbuf + wv * 1088;  // per-wave 64px x 17
        for (int ob = 0; ob < 4; ++ob) {
            int obg = obBase + ob;
            if (obg * 16 >= Cout) continue;    // wave-uniform
            #pragma unroll
            for (int r = 0; r < 4; ++r) {
                float bv = bias ? bias[obg * 16 + lg * 4 + r] : 0.f;
                #pragma unroll
                for (int pt = 0; pt < 4; ++pt)
                    s_ep[(pt * 16 + l16) * 17 + lg * 4 + r] = acc[ob][pt][r] + bv;
            }
            size_t pxg = (size_t)img * HW_SZ + (size_t)y0 * 64 + lane;
            if (outmode == 1) {
                float* op = (float*)outp + pxg * 288 + obg * 16;
                #pragma unroll
                for (int jj = 0; jj < 4; ++jj) {
                    float4 t4;
                    t4.x = s_ep[lane * 17 + jj * 4 + 0];
                    t4.y = s_ep[lane * 17 + jj * 4 + 1];
                    t4.z = s_ep[lane * 17 + jj * 4 + 2];
                    t4.w = s_ep[lane * 17 + jj * 4 + 3];
                    *(float4*)(op + jj * 4) = t4;
                }
            } else {
                unsigned short* op = (unsigned short*)outp + pxg * 256 + obg * 16;
                unsigned v[8];
                #pragma unroll
                for (int j = 0; j < 8; ++j) {
                    unsigned lo = f2bf(s_ep[lane * 17 + 2 * j]);
                    unsigned hi = f2bf(s_ep[lane * 17 + 2 * j + 1]);
                    v[j] = lo | (hi << 16);
                }
                uint4 o0; o0.x = v[0]; o0.y = v[1]; o0.z = v[2]; o0.w = v[3];
                uint4 o1; o1.x = v[4]; o1.y = v[5]; o1.z = v[6]; o1.w = v[7];
                *(uint4*)(op) = o0;
                *(uint4*)(op + 8) = o1;
            }
        }
    }
}

// merged value+qconv. g = ybase + blockIdx.y:
//   g in [0,6):  qconv  img=g/3, mb=g%3  (768->288, f32 pm)  -- heavy, first
//   g in [6,18): value  img=(g-6)>>1, mb=(g-6)&1 (256->256, bf16 pm)
__global__ __launch_bounds__(128, 2) void conv_main(
    int ybase,
    const unsigned short* __restrict__ vin, const unsigned short* __restrict__ wv_,
    const float* __restrict__ bv, unsigned short* __restrict__ vout,
    const unsigned short* __restrict__ qin, const unsigned short* __restrict__ wq_,
    const float* __restrict__ bq, float* __restrict__ qout,
    const unsigned short* __restrict__ zbuf)
{
    __shared__ __align__(16) unsigned short sbuf[2 * 6336];
    int g = ybase + blockIdx.y;
    int y0 = blockIdx.x;
    if (g < 6) {
        int img = g / 3, mb = g - img * 3;
        conv_core(qin + (size_t)img * HW_SZ * 768, wq_, bq, zbuf, (void*)qout,
                  768, 24, 24, 288, mb, y0, 1, img, sbuf);
    } else {
        int h = g - 6; int img = h >> 1, mb = h & 1;
        conv_core(vin + (size_t)img * HW_SZ * 256, wv_, bv, zbuf, (void*)vout,
                  256, 8, 16, 256, mb, y0, 0, img, sbuf);
    }
}

// out conv: grid (64, 4) = (row, img*2+mb). NCHW f32 -> d_out.
__global__ __launch_bounds__(128, 2) void conv_out_k(
    const unsigned short* __restrict__ din, const unsigned short* __restrict__ wo_,
    const float* __restrict__ bo, float* __restrict__ outp,
    const unsigned short* __restrict__ zbuf)
{
    __shared__ __align__(16) unsigned short sbuf[2 * 6336];
    int img = blockIdx.y >> 1, mb = blockIdx.y & 1;
    conv_core(din + (size_t)img * HW_SZ * 256, wo_, bo, zbuf, (void*)outp,
              256, 8, 16, 256, mb, blockIdx.x, 2, img, sbuf);
}

// ---------------- deform sampling (8 channels / thread, 16B gathers) ----------
__global__ __launch_bounds__(256) void deform_kernel(
    const unsigned short* __restrict__ value_bf,
    const float* __restrict__ qout,
    const float* __restrict__ refp,
    const float* __restrict__ flow_fwd,
    const float* __restrict__ flow_bwd,
    unsigned short* __restrict__ dout)
{
    int gid = blockIdx.x * 256 + threadIdx.x;
    int d8 = gid & 3;
    int m = (gid >> 2) & 7;
    int q = (gid >> 5) & 4095;
    int b = gid >> 17;

    size_t bq = (size_t)b * HW_SZ + q;
    const float* qbase = qout + bq * 288;
    const float* al = qbase + 192 + m * 12;

    float lg[12];
    float mx = -1e30f;
    #pragma unroll
    for (int i = 0; i < 12; i++) { lg[i] = al[i]; mx = fmaxf(mx, lg[i]); }
    float s = 0.f;
    #pragma unroll
    for (int i = 0; i < 12; i++) { lg[i] = __expf(lg[i] - mx); s += lg[i]; }
    float inv = 1.f / s;

    const float* op = qbase + m * 24;
    const float* rp = refp + bq * 6;

    float acc[8];
    #pragma unroll
    for (int i = 0; i < 8; ++i) acc[i] = 0.f;

    #pragma unroll
    for (int t = 0; t < 3; t++) {
        float fx = 0.f, fy = 0.f;
        if (t == 0) {
            fx = flow_bwd[((b * 2 + 0) * 2 + 0) * HW_SZ + q];
            fy = flow_bwd[((b * 2 + 0) * 2 + 1) * HW_SZ + q];
        } else if (t == 2) {
            fx = flow_fwd[((b * 2 + 1) * 2 + 0) * HW_SZ + q];
            fy = flow_fwd[((b * 2 + 1) * 2 + 1) * HW_SZ + q];
        }
        float rx = rp[t * 2 + 0], ry = rp[t * 2 + 1];
        const unsigned short* vb =
            value_bf + (size_t)(b * 3 + t) * (HW_SZ * 256) + m * 32 + d8 * 8;
        #pragma unroll
        for (int pp = 0; pp < 4; pp++) {
            float ox = op[t * 8 + pp * 2 + 0] + fx;
            float oy = op[t * 8 + pp * 2 + 1] + fy;
            float aw = lg[t * 4 + pp] * inv;
            float x = rx * 64.f + ox - 0.5f;
            float y = ry * 64.f + oy - 0.5f;
            float x0f = floorf(x), y0f = floorf(y);
            float wx = x - x0f, wy = y - y0f;
            int x0 = (int)x0f, y0 = (int)y0f;
            int x1 = x0 + 1, y1 = y0 + 1;
            bool vx0 = (x0 >= 0) & (x0 < 64), vx1 = (x1 >= 0) & (x1 < 64);
            bool vy0 = (y0 >= 0) & (y0 < 64), vy1 = (y1 >= 0) & (y1 < 64);
            int cx0 = min(max(x0, 0), 63), cx1 = min(max(x1, 0), 63);
            int cy0 = min(max(y0, 0), 63), cy1 = min(max(y1, 0), 63);
            float w00 = (1.f - wx) * (1.f - wy) * ((vx0 & vy0) ? 1.f : 0.f) * aw;
            float w10 = wx * (1.f - wy) * ((vx1 & vy0) ? 1.f : 0.f) * aw;
            float w01 = (1.f - wx) * wy * ((vx0 & vy1) ? 1.f : 0.f) * aw;
            float w11 = wx * wy * ((vx1 & vy1) ? 1.f : 0.f) * aw;
            short8 v00 = *(const short8*)(vb + (cy0 * 64 + cx0) * 256);
            short8 v10 = *(const short8*)(vb + (cy0 * 64 + cx1) * 256);
            short8 v01 = *(const short8*)(vb + (cy1 * 64 + cx0) * 256);
            short8 v11 = *(const short8*)(vb + (cy1 * 64 + cx1) * 256);
            #pragma unroll
            for (int i = 0; i < 8; ++i) {
                acc[i] += w00 * bf2f((unsigned short)v00[i])
                        + w10 * bf2f((unsigned short)v10[i])
                        + w01 * bf2f((unsigned short)v01[i])
                        + w11 * bf2f((unsigned short)v11[i]);
            }
        }
    }
    unsigned pk[4];
    #pragma unroll
    for (int j = 0; j < 4; ++j)
        pk[j] = (unsigned)f2bf(acc[2 * j]) | ((unsigned)f2bf(acc[2 * j + 1]) << 16);
    uint4 o; o.x = pk[0]; o.y = pk[1]; o.z = pk[2]; o.w = pk[3];
    *(uint4*)(dout + bq * 256 + m * 32 + d8 * 8) = o;
}

extern "C" void kernel_launch(void* const* d_in, const int* in_sizes, int n_in,
                              void* d_out, int out_size, void* d_ws, size_t ws_size,
                              hipStream_t stream) {
    const float* query   = (const float*)d_in[0];
    const float* refp    = (const float*)d_in[1];
    const float* inflat  = (const float*)d_in[2];
    const float* flowf   = (const float*)d_in[6];
    const float* flowb   = (const float*)d_in[7];
    const float* w_value = (const float*)d_in[8];
    const float* b_value = (const float*)d_in[9];
    const float* w_off   = (const float*)d_in[10];
    const float* b_off   = (const float*)d_in[11];
    const float* w_attn  = (const float*)d_in[12];
    const float* b_attn  = (const float*)d_in[13];
    const float* w_out   = (const float*)d_in[14];
    const float* b_out   = (const float*)d_in[15];

    char* ws = (char*)d_ws;
    unsigned short* wpk_v    = (unsigned short*)(ws);                    // 1,179,648
    unsigned short* wpk_q    = (unsigned short*)(ws + 1179648);          // 5,308,416
    unsigned short* wpk_o    = (unsigned short*)(ws + 6488064);          // 1,179,648
    float*          qbias    = (float*)(ws + 7667712);                   // 1,536
    float*          zbuf     = (float*)(ws + 7669248);                   // 64
    unsigned short* value_bf = (unsigned short*)(ws + 7669760);          // 12,582,912
    unsigned short* qin_bf   = (unsigned short*)(ws + 20252672);         // 12,582,912
    unsigned short* vin_bf   = (unsigned short*)(ws + 32835584);         // 12,582,912

    const bool big = ws_size >= 54855680ull;
    float* qout = big ? (float*)(ws + 45418496)
                      : (float*)(ws + 32835584);   // small: over vin_bf
    unsigned short* dout_bf = big
        ? (unsigned short*)(ws + 1179648)          // over wpk_q (dead after convs)
        : (unsigned short*)(ws + 42272768);

    // 1) fused prep: transposes + weight repacks (incl. pad zero-fill) + biases
    prep_fused<<<dim3(6354), dim3(256), 0, stream>>>(
        inflat, query, vin_bf, qin_bf,
        w_value, w_off, w_attn, w_out, b_off, b_attn,
        wpk_v, wpk_q, wpk_o, qbias, zbuf);

    // 2) convs (q-groups first for tail balance)
    if (big) {
        conv_main<<<dim3(64, 18), dim3(128), 0, stream>>>(
            0, vin_bf, wpk_v, b_value, value_bf, qin_bf, wpk_q, qbias, qout,
            (const unsigned short*)zbuf);
    } else {
        // small ws: qout aliases vin_bf -> run value conv first, then qconv
        conv_main<<<dim3(64, 12), dim3(128), 0, stream>>>(
            6, vin_bf, wpk_v, b_value, value_bf, qin_bf, wpk_q, qbias, qout,
            (const unsigned short*)zbuf);
        conv_main<<<dim3(64, 6), dim3(128), 0, stream>>>(
            0, vin_bf, wpk_v, b_value, value_bf, qin_bf, wpk_q, qbias, qout,
            (const unsigned short*)zbuf);
    }

    // 3) deform sampling (8 ch/thread, 16B gathers)
    deform_kernel<<<dim3(1024), dim3(256), 0, stream>>>(
        value_bf, qout, refp, flowf, flowb, dout_bf);

    // 4) output conv -> d_out (NCHW f32)
    conv_out_k<<<dim3(64, 4), dim3(128), 0, stream>>>(
        dout_bf, wpk_o, b_out, (float*)d_out, (const unsigned short*)zbuf);
}